// Round 4
// baseline (1262.126 us; speedup 1.0000x reference)
//
#include <hip/hip_runtime.h>
#include <stdint.h>
#include <math.h>

// Problem constants
constexpr int Nn  = 32768;          // B*H*W = 32*32*32
constexpr int Kk  = 1024;

// d_out layout (floats)
constexpr int OUT0_N   = 32 * 64 * 1024;       // 2097152 (z_st, [B,D,H,W])
constexpr int OUT_LOSS = OUT0_N;               // 2097152
constexpr int OUT_PERP = OUT0_N + 1;           // 2097153
constexpr int OUT_ENC  = OUT0_N + 2;           // 2097154

// d_ws layout (bytes): [0]=loss double, [8]=done counter, [64]=counts u32[1024],
// [4160]=minkey u64[32768] (256KB). minkey must live in ws (NOT the enc output
// region) because the finish kernel reads it while writing all of enc.
constexpr size_t WS_LOSS = 0;
constexpr size_t WS_DONE = 8;
constexpr size_t WS_CNT  = 64;
constexpr size_t WS_KEY  = 4160;

// ---------------------------------------------------------------------------
// numpy-bit-exact 64-elem squared-norm: tt[d]=fl(x*x), 8 stride-8 sequential
// accumulators, pairwise combine. Contraction OFF. p: 16B-aligned, contiguous.
// ---------------------------------------------------------------------------
__device__ __forceinline__ float norm64v(const float4* __restrict__ p) {
#pragma clang fp contract(off)
    float tt[64];
#pragma unroll
    for (int q = 0; q < 16; ++q) {
        float4 v = p[q];
        tt[4 * q + 0] = v.x * v.x;
        tt[4 * q + 1] = v.y * v.y;
        tt[4 * q + 2] = v.z * v.z;
        tt[4 * q + 3] = v.w * v.w;
    }
    float r[8];
#pragma unroll
    for (int j = 0; j < 8; ++j) r[j] = tt[j];
#pragma unroll
    for (int i = 8; i < 64; i += 8)
#pragma unroll
        for (int j = 0; j < 8; ++j) r[j] += tt[i + j];
    return ((r[0] + r[1]) + (r[2] + r[3])) + ((r[4] + r[5]) + (r[6] + r[7]));
}

__device__ __forceinline__ uint32_t fsort(float f) {
    uint32_t b = __float_as_uint(f);
    return (b & 0x80000000u) ? ~b : (b | 0x80000000u);
}

// ---------------------------------------------------------------------------
// dist kernel: 2048 blocks = 256 rowgroups x 8 codegroups; 256 thr (16x16);
// per-thread 8x8; BOTH tiles staged in LDS (stride 68 floats, conflict-free).
// R3 lesson: reading e-fragments from global per-iteration is latency-bound
// (146 us, VALUBusy 33%); all-LDS is LDS-throughput-bound (~55 us). d4 loop
// stays unroll-1 (full unroll spilled acc -> 4.9 GB scratch, R1 lesson).
// Winner per row goes out via device atomicMin on a packed u64 key
// (sortable_dist_bits<<32 | code) -> exact numpy argmin incl. tie-to-lowest.
// ---------------------------------------------------------------------------
__global__ __launch_bounds__(256, 2)
void dist_kernel(const float* __restrict__ z_e, const float* __restrict__ emb,
                 unsigned long long* __restrict__ minkey) {
    __shared__ float xs[128 * 68];   // [row][d]
    __shared__ float es[128 * 68];   // [code][d]
    __shared__ float An_s[128];
    __shared__ float Bn_s[128];
    const int tid = threadIdx.x;
    const int rg = blockIdx.x >> 3, cg = blockIdx.x & 7;
    const int n0 = rg * 128;
    const int b = n0 >> 10, hw0 = n0 & 1023;
    const float* zb = z_e + (size_t)b * 65536 + hw0;

    // stage x-tile: 4 coalesced d-slices per float4 LDS write
    {
        int hwi = tid & 127;
        int d4g = tid >> 7;   // 0..1
#pragma unroll
        for (int it = 0; it < 8; ++it) {
            int dbase = (d4g + it * 2) * 4;
            float4 v;
            v.x = zb[(size_t)(dbase + 0) * 1024 + hwi];
            v.y = zb[(size_t)(dbase + 1) * 1024 + hwi];
            v.z = zb[(size_t)(dbase + 2) * 1024 + hwi];
            v.w = zb[(size_t)(dbase + 3) * 1024 + hwi];
            *(float4*)&xs[hwi * 68 + dbase] = v;
        }
    }
    // stage e-tile: contiguous 32KB, coalesced float4
    {
        const float4* ep = (const float4*)(emb + (size_t)cg * 128 * 64);
#pragma unroll
        for (int it = 0; it < 8; ++it) {
            int j = tid + it * 256;      // 0..2047
            float4 v = ep[j];
            int c = j >> 4, d4 = j & 15;
            *(float4*)&es[c * 68 + d4 * 4] = v;
        }
    }
    __syncthreads();

    // in-block norms from the staged tiles (identical bits to global)
    if (tid < 128) {
        An_s[tid] = norm64v((const float4*)&xs[tid * 68]);
    } else {
        int c = tid - 128;
        Bn_s[c] = norm64v((const float4*)&es[c * 68]);
    }
    __syncthreads();

    const int tx = tid & 15, ty = tid >> 4;
    float acc[8][8];
#pragma unroll
    for (int i = 0; i < 8; ++i)
#pragma unroll
        for (int j = 0; j < 8; ++j) acc[i][j] = 0.0f;

#pragma unroll 1
    for (int d4 = 0; d4 < 16; ++d4) {
        float4 xv[8], ev[8];
#pragma unroll
        for (int i = 0; i < 8; ++i) xv[i] = *(const float4*)&xs[(ty + 16 * i) * 68 + d4 * 4];
#pragma unroll
        for (int j = 0; j < 8; ++j) ev[j] = *(const float4*)&es[(tx + 16 * j) * 68 + d4 * 4];
#pragma unroll
        for (int i = 0; i < 8; ++i)
#pragma unroll
            for (int j = 0; j < 8; ++j) {
                float a = acc[i][j];
                a = __builtin_fmaf(xv[i].x, ev[j].x, a);
                a = __builtin_fmaf(xv[i].y, ev[j].y, a);
                a = __builtin_fmaf(xv[i].z, ev[j].z, a);
                a = __builtin_fmaf(xv[i].w, ev[j].w, a);
                acc[i][j] = a;
            }
    }

    // epilogue: dist = fl(fl(A+B) - 2C); per-row min over this block's codes
    float Ar[8], Bc[8];
#pragma unroll
    for (int i = 0; i < 8; ++i) Ar[i] = An_s[ty + 16 * i];
#pragma unroll
    for (int j = 0; j < 8; ++j) Bc[j] = Bn_s[tx + 16 * j];

#pragma unroll
    for (int i = 0; i < 8; ++i) {
        unsigned long long best = ~0ULL;
#pragma unroll
        for (int j = 0; j < 8; ++j) {
            float s = Ar[i] + Bc[j];
            float dist = s - 2.0f * acc[i][j];
            unsigned long long key = ((unsigned long long)fsort(dist) << 32)
                                   | (unsigned)(cg * 128 + tx + 16 * j);
            best = (key < best) ? key : best;
        }
#pragma unroll
        for (int m = 1; m < 16; m <<= 1) {
            unsigned long long o = __shfl_xor(best, m, 64);
            best = (o < best) ? o : best;
        }
        if (tx == 0) atomicMin(&minkey[n0 + ty + 16 * i], best);
    }
}

// ---------------------------------------------------------------------------
// finish kernel: grid 8192 x 256, 4 rows/block. Reads minkey -> code; writes
// z_st (= z + fl(z_q - z)), one-hot encodings, counts, fp64 loss partial.
// Last block to finish (done-counter + threadfence) computes loss/perplexity.
// ---------------------------------------------------------------------------
__global__ void finish_kernel(const float* __restrict__ z_e,
                              const float* __restrict__ emb,
                              const unsigned long long* __restrict__ minkey,
                              uint32_t* __restrict__ counts,
                              double* __restrict__ loss_sum,
                              uint32_t* __restrict__ done,
                              float* __restrict__ out) {
    __shared__ uint32_t scode[4];
    __shared__ double lred[4];
    const int t = threadIdx.x;
    const int r4 = blockIdx.x * 4;                 // rows r4..r4+3 (same b)
    if (t < 4) {
        uint32_t code = (uint32_t)minkey[r4 + t];
        scode[t] = code;
        atomicAdd(&counts[code], 1u);
    }
    __syncthreads();

    // z_st + loss: 256 elems, thread t -> row r4+(t&3), d = t>>2
    {
        const int b = r4 >> 10, hw = (r4 & 1023) + (t & 3);
        const int d = t >> 2;
        const size_t off = (size_t)b * 65536 + (size_t)d * 1024 + hw;
        float z  = z_e[off];
        float zq = emb[(size_t)scode[t & 3] * 64 + d];
        float tt = zq - z;                 // fl(z_q - z), as in np
        out[off] = z + tt;                 // straight-through value
        double ls = (double)tt * (double)tt;
#pragma unroll
        for (int m = 32; m >= 1; m >>= 1) ls += __shfl_down(ls, m, 64);
        if ((t & 63) == 0) lred[t >> 6] = ls;
    }
    __syncthreads();
    if (t == 0) atomicAdd(loss_sum, lred[0] + lred[1] + lred[2] + lred[3]);

    // one-hot: 4 rows x 256 float4 (1KB contiguous per wave-instr)
    float* enc = out + OUT_ENC;
#pragma unroll
    for (int i = 0; i < 4; ++i) {
        uint32_t code = scode[i];
        uint32_t c0 = (uint32_t)(t * 4);
        float4 v;
        v.x = (code == c0 + 0u) ? 1.0f : 0.0f;
        v.y = (code == c0 + 1u) ? 1.0f : 0.0f;
        v.z = (code == c0 + 2u) ? 1.0f : 0.0f;
        v.w = (code == c0 + 3u) ? 1.0f : 0.0f;
        ((float4*)enc)[(size_t)(r4 + i) * 256 + t] = v;
    }

    // completion: last block computes the scalars
    __threadfence();
    __shared__ uint32_t lastflag;
    if (t == 0) lastflag = atomicAdd(done, 1u);
    __syncthreads();
    if (lastflag == 8191) {
        __shared__ double red[4];
        double h = 0.0;
        for (int i = t; i < Kk; i += 256) {
            double p = (double)counts[i] * (1.0 / 32768.0);
            h += p * log(p + 1e-10);
        }
#pragma unroll
        for (int m = 32; m >= 1; m >>= 1) h += __shfl_down(h, m, 64);
        if ((t & 63) == 0) red[t >> 6] = h;
        __syncthreads();
        if (t == 0) {
            double H = red[0] + red[1] + red[2] + red[3];
            out[OUT_PERP] = (float)exp(-H);
            float m32 = (float)(loss_sum[0] * (1.0 / 2097152.0));
            out[OUT_LOSS] = m32 + 0.25f * m32;   // q + 0.25*e, q==e numerically
        }
    }
}

extern "C" void kernel_launch(void* const* d_in, const int* in_sizes, int n_in,
                              void* d_out, int out_size, void* d_ws, size_t ws_size,
                              hipStream_t stream) {
    const float* z_e = (const float*)d_in[0];
    const float* emb = (const float*)d_in[1];
    float* out = (float*)d_out;
    char* ws = (char*)d_ws;

    double*   loss_sum = (double*)(ws + WS_LOSS);
    uint32_t* done     = (uint32_t*)(ws + WS_DONE);
    uint32_t* counts   = (uint32_t*)(ws + WS_CNT);
    unsigned long long* minkey = (unsigned long long*)(ws + WS_KEY);

    // ws poisoned 0xAA every call: zero loss/done/counts, 0xFF the minkeys
    hipMemsetAsync(ws, 0, WS_KEY, stream);
    hipMemsetAsync(ws + WS_KEY, 0xFF, (size_t)Nn * 8, stream);

    dist_kernel<<<2048, 256, 0, stream>>>(z_e, emb, minkey);
    finish_kernel<<<8192, 256, 0, stream>>>(z_e, emb, minkey, counts, loss_sum, done, out);
}

// Round 5
// 235.983 us; speedup vs baseline: 5.3484x; 5.3484x over previous
//
#include <hip/hip_runtime.h>
#include <stdint.h>
#include <math.h>

// Problem constants
constexpr int Nn  = 32768;          // B*H*W = 32*32*32
constexpr int Kk  = 1024;

// d_out layout (floats)
constexpr int OUT0_N   = 32 * 64 * 1024;       // 2097152 (z_st, [B,D,H,W])
constexpr int OUT_LOSS = OUT0_N;               // 2097152
constexpr int OUT_PERP = OUT0_N + 1;           // 2097153
constexpr int OUT_ENC  = OUT0_N + 2;           // 2097154

// d_ws layout (bytes):
//   [0      .. 4096)   counts u32[1024]            (memset 0)
//   [4096   .. 69632)  loss partials double[8192]  (fully written by finish)
//   [69632  .. 331776) minkey u64[32768]           (memset 0xFF)
// R4 lesson: NO single-address atomics at grid scale — 8192 fp64 atomicAdds +
// 8192 done-counter atomics to one address serialized at ~157 cyc each = 1 ms.
constexpr size_t WS_CNT = 0;
constexpr size_t WS_LP  = 4096;
constexpr size_t WS_KEY = 69632;

// ---------------------------------------------------------------------------
// numpy-bit-exact 64-elem squared-norm: tt[d]=fl(x*x), 8 stride-8 sequential
// accumulators, pairwise combine. Contraction OFF. p: 16B-aligned, contiguous.
// ---------------------------------------------------------------------------
__device__ __forceinline__ float norm64v(const float4* __restrict__ p) {
#pragma clang fp contract(off)
    float tt[64];
#pragma unroll
    for (int q = 0; q < 16; ++q) {
        float4 v = p[q];
        tt[4 * q + 0] = v.x * v.x;
        tt[4 * q + 1] = v.y * v.y;
        tt[4 * q + 2] = v.z * v.z;
        tt[4 * q + 3] = v.w * v.w;
    }
    float r[8];
#pragma unroll
    for (int j = 0; j < 8; ++j) r[j] = tt[j];
#pragma unroll
    for (int i = 8; i < 64; i += 8)
#pragma unroll
        for (int j = 0; j < 8; ++j) r[j] += tt[i + j];
    return ((r[0] + r[1]) + (r[2] + r[3])) + ((r[4] + r[5]) + (r[6] + r[7]));
}

__device__ __forceinline__ uint32_t fsort(float f) {
    uint32_t b = __float_as_uint(f);
    return (b & 0x80000000u) ? ~b : (b | 0x80000000u);
}

// ---------------------------------------------------------------------------
// dist kernel (unchanged from R4 — measured ~55-60 us, LDS-throughput-bound):
// 2048 blocks = 256 rowgroups x 8 codegroups; 256 thr (16x16); per-thread 8x8;
// both tiles in LDS (stride 68, conflict-free). unroll-1 K-loop (R1: full
// unroll spilled). Winner via atomicMin on packed u64 key (32768 distinct
// addresses, 8-way contention — cheap). Exact numpy argmin incl. ties.
// ---------------------------------------------------------------------------
__global__ __launch_bounds__(256, 2)
void dist_kernel(const float* __restrict__ z_e, const float* __restrict__ emb,
                 unsigned long long* __restrict__ minkey) {
    __shared__ float xs[128 * 68];   // [row][d]
    __shared__ float es[128 * 68];   // [code][d]
    __shared__ float An_s[128];
    __shared__ float Bn_s[128];
    const int tid = threadIdx.x;
    const int rg = blockIdx.x >> 3, cg = blockIdx.x & 7;
    const int n0 = rg * 128;
    const int b = n0 >> 10, hw0 = n0 & 1023;
    const float* zb = z_e + (size_t)b * 65536 + hw0;

    // stage x-tile: 4 coalesced d-slices per float4 LDS write
    {
        int hwi = tid & 127;
        int d4g = tid >> 7;   // 0..1
#pragma unroll
        for (int it = 0; it < 8; ++it) {
            int dbase = (d4g + it * 2) * 4;
            float4 v;
            v.x = zb[(size_t)(dbase + 0) * 1024 + hwi];
            v.y = zb[(size_t)(dbase + 1) * 1024 + hwi];
            v.z = zb[(size_t)(dbase + 2) * 1024 + hwi];
            v.w = zb[(size_t)(dbase + 3) * 1024 + hwi];
            *(float4*)&xs[hwi * 68 + dbase] = v;
        }
    }
    // stage e-tile: contiguous 32KB, coalesced float4
    {
        const float4* ep = (const float4*)(emb + (size_t)cg * 128 * 64);
#pragma unroll
        for (int it = 0; it < 8; ++it) {
            int j = tid + it * 256;      // 0..2047
            float4 v = ep[j];
            int c = j >> 4, d4 = j & 15;
            *(float4*)&es[c * 68 + d4 * 4] = v;
        }
    }
    __syncthreads();

    // in-block norms from the staged tiles (identical bits to global)
    if (tid < 128) {
        An_s[tid] = norm64v((const float4*)&xs[tid * 68]);
    } else {
        int c = tid - 128;
        Bn_s[c] = norm64v((const float4*)&es[c * 68]);
    }
    __syncthreads();

    const int tx = tid & 15, ty = tid >> 4;
    float acc[8][8];
#pragma unroll
    for (int i = 0; i < 8; ++i)
#pragma unroll
        for (int j = 0; j < 8; ++j) acc[i][j] = 0.0f;

#pragma unroll 1
    for (int d4 = 0; d4 < 16; ++d4) {
        float4 xv[8], ev[8];
#pragma unroll
        for (int i = 0; i < 8; ++i) xv[i] = *(const float4*)&xs[(ty + 16 * i) * 68 + d4 * 4];
#pragma unroll
        for (int j = 0; j < 8; ++j) ev[j] = *(const float4*)&es[(tx + 16 * j) * 68 + d4 * 4];
#pragma unroll
        for (int i = 0; i < 8; ++i)
#pragma unroll
            for (int j = 0; j < 8; ++j) {
                float a = acc[i][j];
                a = __builtin_fmaf(xv[i].x, ev[j].x, a);
                a = __builtin_fmaf(xv[i].y, ev[j].y, a);
                a = __builtin_fmaf(xv[i].z, ev[j].z, a);
                a = __builtin_fmaf(xv[i].w, ev[j].w, a);
                acc[i][j] = a;
            }
    }

    // epilogue: dist = fl(fl(A+B) - 2C); per-row min over this block's codes
    float Ar[8], Bc[8];
#pragma unroll
    for (int i = 0; i < 8; ++i) Ar[i] = An_s[ty + 16 * i];
#pragma unroll
    for (int j = 0; j < 8; ++j) Bc[j] = Bn_s[tx + 16 * j];

#pragma unroll
    for (int i = 0; i < 8; ++i) {
        unsigned long long best = ~0ULL;
#pragma unroll
        for (int j = 0; j < 8; ++j) {
            float s = Ar[i] + Bc[j];
            float dist = s - 2.0f * acc[i][j];
            unsigned long long key = ((unsigned long long)fsort(dist) << 32)
                                   | (unsigned)(cg * 128 + tx + 16 * j);
            best = (key < best) ? key : best;
        }
#pragma unroll
        for (int m = 1; m < 16; m <<= 1) {
            unsigned long long o = __shfl_xor(best, m, 64);
            best = (o < best) ? o : best;
        }
        if (tx == 0) atomicMin(&minkey[n0 + ty + 16 * i], best);
    }
}

// ---------------------------------------------------------------------------
// finish kernel: grid 8192 x 256, 4 rows/block. minkey -> code; writes z_st
// (= z + fl(z_q - z)), one-hot encodings, counts (1024-way spread atomics),
// and a PLAIN-STORE per-block fp64 loss partial. No fences, no same-address
// atomics (R4 lesson).
// ---------------------------------------------------------------------------
__global__ void finish_kernel(const float* __restrict__ z_e,
                              const float* __restrict__ emb,
                              const unsigned long long* __restrict__ minkey,
                              uint32_t* __restrict__ counts,
                              double* __restrict__ lp,
                              float* __restrict__ out) {
    __shared__ uint32_t scode[4];
    __shared__ double lred[4];
    const int t = threadIdx.x;
    const int r4 = blockIdx.x * 4;                 // rows r4..r4+3 (same b)
    if (t < 4) {
        uint32_t code = (uint32_t)minkey[r4 + t];
        scode[t] = code;
        atomicAdd(&counts[code], 1u);
    }
    __syncthreads();

    // z_st + loss: 256 elems, thread t -> row r4+(t&3), d = t>>2
    {
        const int b = r4 >> 10, hw = (r4 & 1023) + (t & 3);
        const int d = t >> 2;
        const size_t off = (size_t)b * 65536 + (size_t)d * 1024 + hw;
        float z  = z_e[off];
        float zq = emb[(size_t)scode[t & 3] * 64 + d];
        float tt = zq - z;                 // fl(z_q - z), as in np
        out[off] = z + tt;                 // straight-through value
        double ls = (double)tt * (double)tt;
#pragma unroll
        for (int m = 32; m >= 1; m >>= 1) ls += __shfl_down(ls, m, 64);
        if ((t & 63) == 0) lred[t >> 6] = ls;
    }
    __syncthreads();
    if (t == 0) lp[blockIdx.x] = lred[0] + lred[1] + lred[2] + lred[3];

    // one-hot: 4 rows x 256 float4 (1KB contiguous per wave-instr)
    float* enc = out + OUT_ENC;
#pragma unroll
    for (int i = 0; i < 4; ++i) {
        uint32_t code = scode[i];
        uint32_t c0 = (uint32_t)(t * 4);
        float4 v;
        v.x = (code == c0 + 0u) ? 1.0f : 0.0f;
        v.y = (code == c0 + 1u) ? 1.0f : 0.0f;
        v.z = (code == c0 + 2u) ? 1.0f : 0.0f;
        v.w = (code == c0 + 3u) ? 1.0f : 0.0f;
        ((float4*)enc)[(size_t)(r4 + i) * 256 + t] = v;
    }
}

// ---------------------------------------------------------------------------
// scalar kernel: one block; sum 8192 fp64 loss partials + counts entropy.
// Stream ordering (kernel boundary) provides coherence — no fence needed.
// ---------------------------------------------------------------------------
__global__ void scalar_kernel(const uint32_t* __restrict__ counts,
                              const double* __restrict__ lp,
                              float* __restrict__ out) {
    __shared__ double redl[4], redh[4];
    const int t = threadIdx.x;   // 256
    double ls = 0.0;
    for (int i = t; i < 8192; i += 256) ls += lp[i];
    double h = 0.0;
    for (int i = t; i < Kk; i += 256) {
        double p = (double)counts[i] * (1.0 / 32768.0);
        h += p * log(p + 1e-10);
    }
#pragma unroll
    for (int m = 32; m >= 1; m >>= 1) { ls += __shfl_down(ls, m, 64); h += __shfl_down(h, m, 64); }
    if ((t & 63) == 0) { redl[t >> 6] = ls; redh[t >> 6] = h; }
    __syncthreads();
    if (t == 0) {
        double L = redl[0] + redl[1] + redl[2] + redl[3];
        double H = redh[0] + redh[1] + redh[2] + redh[3];
        out[OUT_PERP] = (float)exp(-H);
        float m32 = (float)(L * (1.0 / 2097152.0));
        out[OUT_LOSS] = m32 + 0.25f * m32;   // q + 0.25*e, q==e numerically
    }
}

extern "C" void kernel_launch(void* const* d_in, const int* in_sizes, int n_in,
                              void* d_out, int out_size, void* d_ws, size_t ws_size,
                              hipStream_t stream) {
    const float* z_e = (const float*)d_in[0];
    const float* emb = (const float*)d_in[1];
    float* out = (float*)d_out;
    char* ws = (char*)d_ws;

    uint32_t* counts = (uint32_t*)(ws + WS_CNT);
    double*   lp     = (double*)(ws + WS_LP);
    unsigned long long* minkey = (unsigned long long*)(ws + WS_KEY);

    // ws poisoned 0xAA every call: zero counts, 0xFF the minkeys
    hipMemsetAsync(ws + WS_CNT, 0, 4096, stream);
    hipMemsetAsync(ws + WS_KEY, 0xFF, (size_t)Nn * 8, stream);

    dist_kernel<<<2048, 256, 0, stream>>>(z_e, emb, minkey);
    finish_kernel<<<8192, 256, 0, stream>>>(z_e, emb, minkey, counts, lp, out);
    scalar_kernel<<<1, 256, 0, stream>>>(counts, lp, out);
}